// Round 1
// baseline (7911.730 us; speedup 1.0000x reference)
//
#include <hip/hip_runtime.h>
#include <cstdint>
#include <cstddef>

typedef __bf16 bf16;
typedef __bf16 bf16x8 __attribute__((ext_vector_type(8)));
typedef float f32x4 __attribute__((ext_vector_type(4)));

static __device__ __forceinline__ f32x4 mfma16(bf16x8 a, bf16x8 b, f32x4 c) {
  return __builtin_amdgcn_mfma_f32_16x16x32_bf16(a, b, c, 0, 0, 0);
}

// ---------------------------------------------------------------------------
// GRU step: one GEMM (512 x Ktot) @ (Ktot x 2880) with gate-permuted columns,
// fused GRU elementwise epilogue. Columns permuted as: n' = g*96 + gate*32 + uu
// (g in [0,30), gate in {r,z,n}, uu in [0,32)), orig col = gate*960 + g*32 + uu.
// K layout: [x-part (KXPAD rows) | h-part (960 rows)].
// n-gate needs inn (x-part) and hn (h-part) separately -> accumulator
// checkpoint at k0 == KXPAD.
// ---------------------------------------------------------------------------
struct StepArgs {
  const bf16* X;        // [512][ldx] bf16 input x
  const bf16* Hb;       // [512][960] bf16 prev hidden
  const bf16* Wt;       // [2880][Ktot] bf16, permuted cols, row-major in k
  const float* bA;      // [2880] permuted: r/z: bih+bhh ; n: bih
  const float* bB;      // [2880] permuted: r/z: 0       ; n: bhh
  const float* Hf_prev; // [512][960] f32 prev hidden
  float* Hf_next;       // [512][960] f32 new hidden
  bf16* Hb_next;        // [512][960] bf16 new hidden
  float* out_hidden;    // may be null; base = hid + t*1920 (+960 for layer 1)
  int ldx;
  int KXPAD;
  int Ktot;
  int _pad;
};

__global__ __launch_bounds__(256) void gru_step(StepArgs a0, StepArgs a1) {
  const StepArgs& a = (blockIdx.z == 0) ? a0 : a1;
  __shared__ bf16 ldsB[96 * 40];  // 96 rows x 80 bytes (32 k-elems + pad)

  const int tid = threadIdx.x;
  const int wv = tid >> 6, lane = tid & 63, col = lane & 15, quad = lane >> 4;
  const int g = blockIdx.x;   // 0..29 (column group)
  const int bm = blockIdx.y;  // 0..7  (64-row strip)
  const int mrow = bm * 64 + wv * 16 + col;
  const int Ktot = a.Ktot, KXPAD = a.KXPAD;

  const f32x4 z4 = {0.f, 0.f, 0.f, 0.f};
  f32x4 acc[6] = {z4, z4, z4, z4, z4, z4};
  f32x4 ck4 = z4, ck5 = z4;

  const bf16* Aptr0 = a.X + (size_t)mrow * a.ldx + quad * 8;
  const bf16* Aptr1 = a.Hb + (size_t)mrow * 960 + quad * 8 - KXPAD;
  const bf16* Wg = a.Wt + (size_t)(g * 96) * Ktot;

  for (int k0 = 0; k0 < Ktot; k0 += 32) {
    if (k0 == KXPAD) { ck4 = acc[4]; ck5 = acc[5]; }  // snapshot x-part (inn)
    __syncthreads();
#pragma unroll
    for (int r = 0; r < 3; ++r) {  // stage 96x32 B tile: 768 x 8B chunks
      int idx = r * 256 + tid;
      int n = idx >> 3, c = idx & 7;
      uint2 v = *(const uint2*)(Wg + (size_t)n * Ktot + k0 + c * 4);
      *(uint2*)((char*)ldsB + n * 80 + c * 8) = v;
    }
    __syncthreads();
    const bf16* ap = (k0 < KXPAD) ? (Aptr0 + k0) : (Aptr1 + k0);
    bf16x8 af = *(const bf16x8*)ap;
#pragma unroll
    for (int f = 0; f < 6; ++f) {
      bf16x8 bfr = *(const bf16x8*)((const char*)ldsB + (f * 16 + col) * 80 + quad * 16);
      acc[f] = mfma16(af, bfr, acc[f]);
    }
  }

  // Epilogue: C/D layout col=lane&15 (unit), row=quad*4+reg (batch row).
  // frags 0,1 = r-gate, 2,3 = z-gate, 4,5 = n-gate for units g*32 + f*16+col.
  const int mbase = bm * 64 + wv * 16 + quad * 4;
  const int gbase = g * 96;
#pragma unroll
  for (int f = 0; f < 2; ++f) {
    const int uu = f * 16 + col;
    const int u = g * 32 + uu;
    const float bAr = a.bA[gbase + uu];
    const float bAz = a.bA[gbase + 32 + uu];
    const float bAn = a.bA[gbase + 64 + uu];
    const float bBn = a.bB[gbase + 64 + uu];
    f32x4 R = acc[f], Z = acc[f + 2], Nf = acc[f + 4];
    f32x4 Nx = f ? ck5 : ck4;
#pragma unroll
    for (int r = 0; r < 4; ++r) {
      const int mm = mbase + r;
      float rg = 1.f / (1.f + __expf(-(R[r] + bAr)));
      float zg = 1.f / (1.f + __expf(-(Z[r] + bAz)));
      float inn = Nx[r] + bAn;
      float hn = (Nf[r] - Nx[r]) + bBn;
      float ng = tanhf(fmaf(rg, hn, inn));
      float hold = a.Hf_prev[(size_t)mm * 960 + u];
      float hnew = fmaf(zg, hold - ng, ng);  // (1-z)*n + z*h
      a.Hf_next[(size_t)mm * 960 + u] = hnew;
      a.Hb_next[(size_t)mm * 960 + u] = (bf16)hnew;
      if (a.out_hidden) a.out_hidden[(size_t)mm * 92160 + u] = hnew;
    }
  }
}

// ---------------------------------------------------------------------------
// Final batched linear: outputs[b][t][n] = hid[b][t][960+k] . linW[n][k] + b[n]
// M = 512*48 rows, N = 32, K = 960. A converted f32->bf16 on the fly.
// ---------------------------------------------------------------------------
__global__ __launch_bounds__(256) void final_linear(const float* __restrict__ hid,
                                                    const bf16* __restrict__ Wb,
                                                    const float* __restrict__ bias,
                                                    float* __restrict__ outp) {
  const int tid = threadIdx.x;
  const int wv = tid >> 6, lane = tid & 63, col = lane & 15, quad = lane >> 4;
  const int row = blockIdx.x * 64 + wv * 16 + col;  // 0..24575
  const int b = row / 48, t = row - b * 48;
  const float* arow = hid + (size_t)b * 92160 + (size_t)t * 1920 + 960 + quad * 8;
  const f32x4 z4 = {0.f, 0.f, 0.f, 0.f};
  f32x4 acc0 = z4, acc1 = z4;
  for (int k0 = 0; k0 < 960; k0 += 32) {
    f32x4 x0 = *(const f32x4*)(arow + k0);
    f32x4 x1 = *(const f32x4*)(arow + k0 + 4);
    bf16x8 af;
#pragma unroll
    for (int i = 0; i < 4; ++i) { af[i] = (bf16)x0[i]; af[4 + i] = (bf16)x1[i]; }
    bf16x8 b0 = *(const bf16x8*)(Wb + (size_t)col * 960 + k0 + quad * 8);
    bf16x8 b1 = *(const bf16x8*)(Wb + (size_t)(16 + col) * 960 + k0 + quad * 8);
    acc0 = mfma16(af, b0, acc0);
    acc1 = mfma16(af, b1, acc1);
  }
  const int mbase = blockIdx.x * 64 + wv * 16 + quad * 4;
#pragma unroll
  for (int r = 0; r < 4; ++r) {
    const int mm = mbase + r;
    const int b2 = mm / 48, t2 = mm - b2 * 48;
    float* o = outp + (size_t)b2 * 1536 + (size_t)t2 * 32;
    o[col] = acc0[r] + bias[col];
    o[16 + col] = acc1[r] + bias[16 + col];
  }
}

// ---------------------------------------------------------------------------
// Prep kernels (run each launch; weights arrive fp32, re-poisoned each call)
// ---------------------------------------------------------------------------
__global__ void prep_weight(const float* __restrict__ Wih, const float* __restrict__ Whh,
                            bf16* __restrict__ dst, int Kx, int KXPAD, int Ktot) {
  const int total = 2880 * Ktot;
  for (int e = blockIdx.x * blockDim.x + threadIdx.x; e < total; e += gridDim.x * blockDim.x) {
    int n = e / Ktot, k = e - n * Ktot;
    int g = n / 96, loc = n - g * 96, gate = loc >> 5, uu = loc & 31;
    int c = gate * 960 + g * 32 + uu;
    float v;
    if (k < KXPAD) v = (k < Kx) ? Wih[(size_t)c * Kx + k] : 0.f;
    else v = Whh[(size_t)c * 960 + (k - KXPAD)];
    dst[e] = (bf16)v;
  }
}

// dec layer0 for t>=1: x-part = Wih0 @ linW  (fold the feedback linear)
__global__ void prep_weight_dec0(const float* __restrict__ Wih, const float* __restrict__ Whh,
                                 const float* __restrict__ linW, bf16* __restrict__ dst) {
  const int total = 2880 * 1920;
  for (int e = blockIdx.x * blockDim.x + threadIdx.x; e < total; e += gridDim.x * blockDim.x) {
    int n = e / 1920, k = e - n * 1920;
    int g = n / 96, loc = n - g * 96, gate = loc >> 5, uu = loc & 31;
    int c = gate * 960 + g * 32 + uu;
    float v;
    if (k < 960) {
      float s = 0.f;
      for (int j = 0; j < 32; ++j) s = fmaf(Wih[(size_t)c * 32 + j], linW[(size_t)j * 960 + k], s);
      v = s;
    } else {
      v = Whh[(size_t)c * 960 + (k - 960)];
    }
    dst[e] = (bf16)v;
  }
}

__global__ void prep_bias(const float* __restrict__ bih, const float* __restrict__ bhh,
                          float* __restrict__ bA, float* __restrict__ bB) {
  int n = blockIdx.x * blockDim.x + threadIdx.x;
  if (n >= 2880) return;
  int g = n / 96, loc = n - g * 96, gate = loc >> 5, uu = loc & 31;
  int c = gate * 960 + g * 32 + uu;
  if (gate < 2) { bA[n] = bih[c] + bhh[c]; bB[n] = 0.f; }
  else          { bA[n] = bih[c];          bB[n] = bhh[c]; }
}

__global__ void prep_bias_dec0(const float* __restrict__ bih, const float* __restrict__ bhh,
                               const float* __restrict__ Wih, const float* __restrict__ linb,
                               float* __restrict__ bA, float* __restrict__ bB) {
  int n = blockIdx.x * blockDim.x + threadIdx.x;
  if (n >= 2880) return;
  int g = n / 96, loc = n - g * 96, gate = loc >> 5, uu = loc & 31;
  int c = gate * 960 + g * 32 + uu;
  float bi = bih[c];
  for (int j = 0; j < 32; ++j) bi = fmaf(Wih[(size_t)c * 32 + j], linb[j], bi);
  if (gate < 2) { bA[n] = bi + bhh[c]; bB[n] = 0.f; }
  else          { bA[n] = bi;          bB[n] = bhh[c]; }
}

__global__ void prep_xenc(const float* __restrict__ in_data, bf16* __restrict__ X) {
  int i = blockIdx.x * blockDim.x + threadIdx.x;
  if (i >= 64 * 512 * 32) return;
  int k = i & 31, m = (i >> 5) & 511, t = i >> 14;
  X[i] = (k < 16) ? (bf16)in_data[((size_t)m * 64 + t) * 16 + k] : (bf16)0.f;
}

__global__ void cvt_bf16(const float* __restrict__ s, bf16* __restrict__ d, int n) {
  int i = blockIdx.x * blockDim.x + threadIdx.x;
  if (i < n) d[i] = (bf16)s[i];
}

// ---------------------------------------------------------------------------
extern "C" void kernel_launch(void* const* d_in, const int* in_sizes, int n_in,
                              void* d_out, int out_size, void* d_ws, size_t ws_size,
                              hipStream_t stream) {
  (void)in_sizes; (void)n_in; (void)out_size; (void)ws_size;
  const float* in_data = (const float*)d_in[0];
  const float* last_loc = (const float*)d_in[1];
  const float* eWih0 = (const float*)d_in[3];
  const float* eWhh0 = (const float*)d_in[4];
  const float* ebih0 = (const float*)d_in[5];
  const float* ebhh0 = (const float*)d_in[6];
  const float* eWih1 = (const float*)d_in[7];
  const float* eWhh1 = (const float*)d_in[8];
  const float* ebih1 = (const float*)d_in[9];
  const float* ebhh1 = (const float*)d_in[10];
  const float* dWih0 = (const float*)d_in[11];
  const float* dWhh0 = (const float*)d_in[12];
  const float* dbih0 = (const float*)d_in[13];
  const float* dbhh0 = (const float*)d_in[14];
  const float* dWih1 = (const float*)d_in[15];
  const float* dWhh1 = (const float*)d_in[16];
  const float* dbih1 = (const float*)d_in[17];
  const float* dbhh1 = (const float*)d_in[18];
  const float* linW = (const float*)d_in[19];
  const float* linb = (const float*)d_in[20];
  float* outp = (float*)d_out;

  uint8_t* base = (uint8_t*)d_ws;
  size_t off = 0;
  auto alloc = [&](size_t bytes) -> void* {
    void* p = base + off;
    off += (bytes + 255) & ~(size_t)255;
    return p;
  };
  bf16* WtE0 = (bf16*)alloc(2880ull * 992 * 2);
  bf16* WtE1 = (bf16*)alloc(2880ull * 1920 * 2);
  bf16* WtD0a = (bf16*)alloc(2880ull * 992 * 2);
  bf16* WtD0 = (bf16*)alloc(2880ull * 1920 * 2);
  bf16* WtD1 = (bf16*)alloc(2880ull * 1920 * 2);
  bf16* linWb = (bf16*)alloc(32ull * 960 * 2);
  float* bA_e0 = (float*)alloc(2880 * 4); float* bB_e0 = (float*)alloc(2880 * 4);
  float* bA_e1 = (float*)alloc(2880 * 4); float* bB_e1 = (float*)alloc(2880 * 4);
  float* bA_d0a = (float*)alloc(2880 * 4); float* bB_d0a = (float*)alloc(2880 * 4);
  float* bA_d0 = (float*)alloc(2880 * 4); float* bB_d0 = (float*)alloc(2880 * 4);
  float* bA_d1 = (float*)alloc(2880 * 4); float* bB_d1 = (float*)alloc(2880 * 4);
  bf16* Xenc = (bf16*)alloc(64ull * 512 * 32 * 2);
  bf16* Xloc = (bf16*)alloc(512ull * 32 * 2);
  // hidden state ping/pong buffers (contiguous for one memset)
  const int HS_ELEMS = 512 * 960;
  float* states = (float*)alloc((size_t)HS_ELEMS * (4 * 4 + 4 * 2));
  float* h0f[2] = {states, states + HS_ELEMS};
  float* h1f[2] = {states + 2 * HS_ELEMS, states + 3 * HS_ELEMS};
  bf16* bstates = (bf16*)(states + 4 * HS_ELEMS);
  bf16* h0b[2] = {bstates, bstates + HS_ELEMS};
  bf16* h1b[2] = {bstates + 2 * HS_ELEMS, bstates + 3 * HS_ELEMS};

  // ---- prep ----
  hipMemsetAsync(states, 0, (size_t)HS_ELEMS * (4 * 4 + 4 * 2), stream);
  prep_weight<<<4096, 256, 0, stream>>>(eWih0, eWhh0, WtE0, 16, 32, 992);
  prep_weight<<<8192, 256, 0, stream>>>(eWih1, eWhh1, WtE1, 960, 960, 1920);
  prep_weight<<<4096, 256, 0, stream>>>(dWih0, dWhh0, WtD0a, 32, 32, 992);
  prep_weight_dec0<<<8192, 256, 0, stream>>>(dWih0, dWhh0, linW, WtD0);
  prep_weight<<<8192, 256, 0, stream>>>(dWih1, dWhh1, WtD1, 960, 960, 1920);
  prep_bias<<<12, 256, 0, stream>>>(ebih0, ebhh0, bA_e0, bB_e0);
  prep_bias<<<12, 256, 0, stream>>>(ebih1, ebhh1, bA_e1, bB_e1);
  prep_bias<<<12, 256, 0, stream>>>(dbih0, dbhh0, bA_d0a, bB_d0a);
  prep_bias_dec0<<<12, 256, 0, stream>>>(dbih0, dbhh0, dWih0, linb, bA_d0, bB_d0);
  prep_bias<<<12, 256, 0, stream>>>(dbih1, dbhh1, bA_d1, bB_d1);
  prep_xenc<<<(64 * 512 * 32 + 255) / 256, 256, 0, stream>>>(in_data, Xenc);
  cvt_bf16<<<(512 * 32 + 255) / 256, 256, 0, stream>>>(last_loc, Xloc, 512 * 32);
  cvt_bf16<<<(32 * 960 + 255) / 256, 256, 0, stream>>>(linW, linWb, 32 * 960);

  auto step_args = [](const bf16* X, int ldx, const bf16* Hb, const bf16* Wt,
                      const float* bA, const float* bB, int KXPAD, int Ktot,
                      const float* Hfp, float* Hfn, bf16* Hbn, float* oh) {
    StepArgs s;
    s.X = X; s.ldx = ldx; s.Hb = Hb; s.Wt = Wt; s.bA = bA; s.bB = bB;
    s.KXPAD = KXPAD; s.Ktot = Ktot; s.Hf_prev = Hfp; s.Hf_next = Hfn;
    s.Hb_next = Hbn; s.out_hidden = oh; s._pad = 0;
    return s;
  };

  int p0 = 0, p1 = 0;
  // ---- encoder (L0 step t fused with L1 step t-1) ----
  {
    StepArgs s = step_args(Xenc, 32, h0b[p0], WtE0, bA_e0, bB_e0, 32, 992,
                           h0f[p0], h0f[1 - p0], h0b[1 - p0], nullptr);
    gru_step<<<dim3(30, 8, 1), 256, 0, stream>>>(s, s);
    p0 ^= 1;
  }
  for (int t = 1; t < 64; ++t) {
    StepArgs s0 = step_args(Xenc + (size_t)t * 512 * 32, 32, h0b[p0], WtE0, bA_e0, bB_e0, 32, 992,
                            h0f[p0], h0f[1 - p0], h0b[1 - p0], nullptr);
    StepArgs s1 = step_args(h0b[p0], 960, h1b[p1], WtE1, bA_e1, bB_e1, 960, 1920,
                            h1f[p1], h1f[1 - p1], h1b[1 - p1], nullptr);
    gru_step<<<dim3(30, 8, 2), 256, 0, stream>>>(s0, s1);
    p0 ^= 1; p1 ^= 1;
  }
  {
    StepArgs s1 = step_args(h0b[p0], 960, h1b[p1], WtE1, bA_e1, bB_e1, 960, 1920,
                            h1f[p1], h1f[1 - p1], h1b[1 - p1], nullptr);
    gru_step<<<dim3(30, 8, 1), 256, 0, stream>>>(s1, s1);
    p1 ^= 1;
  }
  // ---- decoder ----
  float* hid = outp + 786432;  // hidden_outputs base (512 x 48 x 1920)
  for (int t = 0; t < 48; ++t) {
    StepArgs s0;
    if (t == 0)
      s0 = step_args(Xloc, 32, h0b[p0], WtD0a, bA_d0a, bB_d0a, 32, 992,
                     h0f[p0], h0f[1 - p0], h0b[1 - p0], hid + (size_t)t * 1920);
    else
      s0 = step_args(h1b[p1], 960, h0b[p0], WtD0, bA_d0, bB_d0, 960, 1920,
                     h0f[p0], h0f[1 - p0], h0b[1 - p0], hid + (size_t)t * 1920);
    gru_step<<<dim3(30, 8, 1), 256, 0, stream>>>(s0, s0);
    p0 ^= 1;
    StepArgs s1 = step_args(h0b[p0], 960, h1b[p1], WtD1, bA_d1, bB_d1, 960, 1920,
                            h1f[p1], h1f[1 - p1], h1b[1 - p1], hid + (size_t)t * 1920 + 960);
    gru_step<<<dim3(30, 8, 1), 256, 0, stream>>>(s1, s1);
    p1 ^= 1;
  }
  // ---- all 48 outputs in one batched GEMM from stored h1 ----
  final_linear<<<384, 256, 0, stream>>>(hid, linWb, linb, outp);
}

// Round 2
// 5863.124 us; speedup vs baseline: 1.3494x; 1.3494x over previous
//
#include <hip/hip_runtime.h>
#include <cstdint>
#include <cstddef>

typedef __bf16 bf16;
typedef __bf16 bf16x8 __attribute__((ext_vector_type(8)));
typedef float f32x4 __attribute__((ext_vector_type(4)));

static __device__ __forceinline__ f32x4 mfma16(bf16x8 a, bf16x8 b, f32x4 c) {
  return __builtin_amdgcn_mfma_f32_16x16x32_bf16(a, b, c, 0, 0, 0);
}

// ---------------------------------------------------------------------------
// GRU step: one GEMM (512 x Ktot) @ (Ktot x 2880) with gate-permuted columns,
// fused GRU elementwise epilogue. Columns permuted: n' = g*96 + gate*32 + uu,
// orig col = gate*960 + g*32 + uu. K = [x-part (KXPAD) | h-part (960)].
// n-gate needs inn (x-part) separate -> accumulator checkpoint at k0==KXPAD.
//
// Tiling: block = 64 rows x 96 cols (one gate group). 4 waves = 2 row-halves
// x 2 unit-halves; wave = 2 m-frags x 3 gate-frags (reads/MFMA = 0.83).
// K-loop: double-buffered LDS (96x32 tile, 80-B pitch rows -> only 2-way
// bank aliasing = free), 2-deep register prefetch of B staging, 1-deep of A.
// One __syncthreads per iter; all global loads get >=1 compute phase in
// flight before their vmcnt wait, so the barrier drain is cheap.
// Grid x = 256 with swizzle: id = q*64 + s*8 + r, g = q*8+r, strip = s ->
// all 8 strips of group g share XCD (id%8 == g%8): B re-reads hit per-XCD L2.
// ---------------------------------------------------------------------------
struct StepArgs {
  const bf16* X;        // [512][ldx] bf16 input x
  const bf16* Hb;       // [512][960] bf16 prev hidden
  const bf16* Wt;       // [2880][Ktot] bf16, permuted cols
  const float* bA;      // [2880] r/z: bih+bhh ; n: bih
  const float* bB;      // [2880] r/z: 0       ; n: bhh
  const float* Hf_prev; // [512][960] f32 prev hidden
  float* Hf_next;       // [512][960] f32 new hidden
  bf16* Hb_next;        // [512][960] bf16 new hidden
  float* out_hidden;    // may be null; base = hid + t*1920 (+960 for layer 1)
  int ldx;
  int KXPAD;
  int Ktot;
  int _pad;
};

__global__ __launch_bounds__(256) void gru_step(StepArgs a0, StepArgs a1) {
  const StepArgs a = (blockIdx.z == 0) ? a0 : a1;
  const int id = blockIdx.x;
  const int gq = id >> 6, bm = (id >> 3) & 7, gr = id & 7;
  const int g = gq * 8 + gr;
  if (g >= 30) return;

  __shared__ bf16 ldsB[2 * 3840];  // two 96x32 tiles, 80-B row pitch

  const int tid = threadIdx.x;
  const int wv = tid >> 6, lane = tid & 63, col = lane & 15, quad = lane >> 4;
  const int mh = wv & 1, uh = wv >> 1;
  const int Ktot = a.Ktot, KXPAD = a.KXPAD;
  const int nb = tid >> 3, cc = tid & 7;

  // B staging: thread covers rows nb, nb+32, nb+64; 8B chunk cc within 32-k row
  const bf16* Wb0 = a.Wt + ((size_t)g * 96 + nb) * Ktot + cc * 4;
  const size_t WrS = (size_t)32 * Ktot;
  char* ldsW = (char*)ldsB + nb * 80 + cc * 8;

  const int rowA = bm * 64 + mh * 32 + col;
  const bf16* Xrow = a.X + (size_t)rowA * a.ldx + quad * 8;
  const bf16* Hrow = a.Hb + (size_t)rowA * 960 + quad * 8 - KXPAD;
  const int ldx16 = 16 * a.ldx;

  const f32x4 z4 = {0.f, 0.f, 0.f, 0.f};
  f32x4 acc[2][3] = {{z4, z4, z4}, {z4, z4, z4}};
  f32x4 ck0 = z4, ck1 = z4;

  uint2 br00, br01, br02, br10, br11, br12;  // 2-deep B prefetch
  bf16x8 ar0, ar1;                           // 1-deep A prefetch

#define STAGE0(K) do { br00 = *(const uint2*)(Wb0 + (K)); \
                       br01 = *(const uint2*)(Wb0 + WrS + (K)); \
                       br02 = *(const uint2*)(Wb0 + 2 * WrS + (K)); } while (0)
#define STAGE1(K) do { br10 = *(const uint2*)(Wb0 + (K)); \
                       br11 = *(const uint2*)(Wb0 + WrS + (K)); \
                       br12 = *(const uint2*)(Wb0 + 2 * WrS + (K)); } while (0)
#define LOADA(K) do { int _k = (K); \
    if (_k < KXPAD) { const bf16* _p = Xrow + _k; ar0 = *(const bf16x8*)_p; ar1 = *(const bf16x8*)(_p + ldx16); } \
    else { const bf16* _p = Hrow + _k; ar0 = *(const bf16x8*)_p; ar1 = *(const bf16x8*)(_p + 16 * 960); } } while (0)

  const char* ldsRd = (char*)ldsB + (uh * 16 + col) * 80 + quad * 16;

#define GRU_ITER(PH) do { \
    if (k0 == KXPAD) { ck0 = acc[0][2]; ck1 = acc[1][2]; } \
    char* _d = ldsW + bufoff; \
    *(uint2*)_d = br##PH##0; \
    *(uint2*)(_d + 32 * 80) = br##PH##1; \
    *(uint2*)(_d + 64 * 80) = br##PH##2; \
    bf16x8 am0 = ar0, am1 = ar1; \
    __syncthreads(); \
    { int _k2 = k0 + 64; if (_k2 >= Ktot) _k2 = 0; STAGE##PH(_k2); } \
    { int _kn = k0 + 32; if (_kn >= Ktot) _kn = 0; LOADA(_kn); } \
    const char* _rp = ldsRd + bufoff; \
    _Pragma("unroll") \
    for (int gate = 0; gate < 3; ++gate) { \
      bf16x8 _bf = *(const bf16x8*)(_rp + gate * (32 * 80)); \
      acc[0][gate] = mfma16(am0, _bf, acc[0][gate]); \
      acc[1][gate] = mfma16(am1, _bf, acc[1][gate]); \
    } \
    k0 += 32; bufoff ^= 7680; \
  } while (0)

  STAGE0(0);
  STAGE1(32 < Ktot ? 32 : 0);
  LOADA(0);
  int k0 = 0, bufoff = 0;
  const int T = Ktot >> 5;
  for (int it = 0; it + 2 <= T; it += 2) {
    GRU_ITER(0);
    GRU_ITER(1);
  }
  if (T & 1) { GRU_ITER(0); }

#undef GRU_ITER
#undef STAGE0
#undef STAGE1
#undef LOADA

  // Epilogue: C/D layout col=lane&15 (unit), row=quad*4+reg (batch row).
  const int uu = uh * 16 + col;
  const int u = g * 32 + uu;
  const int gbase = g * 96;
  const float bAr = a.bA[gbase + uu];
  const float bAz = a.bA[gbase + 32 + uu];
  const float bAn = a.bA[gbase + 64 + uu];
  const float bBn = a.bB[gbase + 64 + uu];
#pragma unroll
  for (int mf = 0; mf < 2; ++mf) {
    f32x4 R = acc[mf][0], Z = acc[mf][1], Nf = acc[mf][2];
    f32x4 Nx = mf ? ck1 : ck0;
    const int mbase = bm * 64 + mh * 32 + mf * 16 + quad * 4;
#pragma unroll
    for (int r = 0; r < 4; ++r) {
      const int mm = mbase + r;
      float rg = 1.f / (1.f + __expf(-(R[r] + bAr)));
      float zg = 1.f / (1.f + __expf(-(Z[r] + bAz)));
      float inn = Nx[r] + bAn;
      float hn = (Nf[r] - Nx[r]) + bBn;
      float ng = tanhf(fmaf(rg, hn, inn));
      float hold = a.Hf_prev[(size_t)mm * 960 + u];
      float hnew = fmaf(zg, hold - ng, ng);  // (1-z)*n + z*h
      a.Hf_next[(size_t)mm * 960 + u] = hnew;
      a.Hb_next[(size_t)mm * 960 + u] = (bf16)hnew;
      if (a.out_hidden) a.out_hidden[(size_t)mm * 92160 + u] = hnew;
    }
  }
}

// ---------------------------------------------------------------------------
// Final batched linear: outputs[b][t][n] = hid[b][t][960+k] . linW[n][k] + b[n]
// M = 512*48 rows, N = 32, K = 960.
// ---------------------------------------------------------------------------
__global__ __launch_bounds__(256) void final_linear(const float* __restrict__ hid,
                                                    const bf16* __restrict__ Wb,
                                                    const float* __restrict__ bias,
                                                    float* __restrict__ outp) {
  const int tid = threadIdx.x;
  const int wv = tid >> 6, lane = tid & 63, col = lane & 15, quad = lane >> 4;
  const int row = blockIdx.x * 64 + wv * 16 + col;  // 0..24575
  const int b = row / 48, t = row - b * 48;
  const float* arow = hid + (size_t)b * 92160 + (size_t)t * 1920 + 960 + quad * 8;
  const f32x4 z4 = {0.f, 0.f, 0.f, 0.f};
  f32x4 acc0 = z4, acc1 = z4;
  for (int k0 = 0; k0 < 960; k0 += 32) {
    f32x4 x0 = *(const f32x4*)(arow + k0);
    f32x4 x1 = *(const f32x4*)(arow + k0 + 4);
    bf16x8 af;
#pragma unroll
    for (int i = 0; i < 4; ++i) { af[i] = (bf16)x0[i]; af[4 + i] = (bf16)x1[i]; }
    bf16x8 b0 = *(const bf16x8*)(Wb + (size_t)col * 960 + k0 + quad * 8);
    bf16x8 b1 = *(const bf16x8*)(Wb + (size_t)(16 + col) * 960 + k0 + quad * 8);
    acc0 = mfma16(af, b0, acc0);
    acc1 = mfma16(af, b1, acc1);
  }
  const int mbase = blockIdx.x * 64 + wv * 16 + quad * 4;
#pragma unroll
  for (int r = 0; r < 4; ++r) {
    const int mm = mbase + r;
    const int b2 = mm / 48, t2 = mm - b2 * 48;
    float* o = outp + (size_t)b2 * 1536 + (size_t)t2 * 32;
    o[col] = acc0[r] + bias[col];
    o[16 + col] = acc1[r] + bias[16 + col];
  }
}

// ---------------------------------------------------------------------------
// Prep kernels (run each launch; weights arrive fp32, re-poisoned each call)
// ---------------------------------------------------------------------------
__global__ void prep_weight(const float* __restrict__ Wih, const float* __restrict__ Whh,
                            bf16* __restrict__ dst, int Kx, int KXPAD, int Ktot) {
  const int total = 2880 * Ktot;
  for (int e = blockIdx.x * blockDim.x + threadIdx.x; e < total; e += gridDim.x * blockDim.x) {
    int n = e / Ktot, k = e - n * Ktot;
    int g = n / 96, loc = n - g * 96, gate = loc >> 5, uu = loc & 31;
    int c = gate * 960 + g * 32 + uu;
    float v;
    if (k < KXPAD) v = (k < Kx) ? Wih[(size_t)c * Kx + k] : 0.f;
    else v = Whh[(size_t)c * 960 + (k - KXPAD)];
    dst[e] = (bf16)v;
  }
}

// dec layer0 for t>=1: x-part = Wih0 @ linW  (fold the feedback linear)
__global__ void prep_weight_dec0(const float* __restrict__ Wih, const float* __restrict__ Whh,
                                 const float* __restrict__ linW, bf16* __restrict__ dst) {
  const int total = 2880 * 1920;
  for (int e = blockIdx.x * blockDim.x + threadIdx.x; e < total; e += gridDim.x * blockDim.x) {
    int n = e / 1920, k = e - n * 1920;
    int g = n / 96, loc = n - g * 96, gate = loc >> 5, uu = loc & 31;
    int c = gate * 960 + g * 32 + uu;
    float v;
    if (k < 960) {
      float s = 0.f;
      for (int j = 0; j < 32; ++j) s = fmaf(Wih[(size_t)c * 32 + j], linW[(size_t)j * 960 + k], s);
      v = s;
    } else {
      v = Whh[(size_t)c * 960 + (k - 960)];
    }
    dst[e] = (bf16)v;
  }
}

__global__ void prep_bias(const float* __restrict__ bih, const float* __restrict__ bhh,
                          float* __restrict__ bA, float* __restrict__ bB) {
  int n = blockIdx.x * blockDim.x + threadIdx.x;
  if (n >= 2880) return;
  int g = n / 96, loc = n - g * 96, gate = loc >> 5, uu = loc & 31;
  int c = gate * 960 + g * 32 + uu;
  if (gate < 2) { bA[n] = bih[c] + bhh[c]; bB[n] = 0.f; }
  else          { bA[n] = bih[c];          bB[n] = bhh[c]; }
}

__global__ void prep_bias_dec0(const float* __restrict__ bih, const float* __restrict__ bhh,
                               const float* __restrict__ Wih, const float* __restrict__ linb,
                               float* __restrict__ bA, float* __restrict__ bB) {
  int n = blockIdx.x * blockDim.x + threadIdx.x;
  if (n >= 2880) return;
  int g = n / 96, loc = n - g * 96, gate = loc >> 5, uu = loc & 31;
  int c = gate * 960 + g * 32 + uu;
  float bi = bih[c];
  for (int j = 0; j < 32; ++j) bi = fmaf(Wih[(size_t)c * 32 + j], linb[j], bi);
  if (gate < 2) { bA[n] = bi + bhh[c]; bB[n] = 0.f; }
  else          { bA[n] = bi;          bB[n] = bhh[c]; }
}

__global__ void prep_xenc(const float* __restrict__ in_data, bf16* __restrict__ X) {
  int i = blockIdx.x * blockDim.x + threadIdx.x;
  if (i >= 64 * 512 * 32) return;
  int k = i & 31, m = (i >> 5) & 511, t = i >> 14;
  X[i] = (k < 16) ? (bf16)in_data[((size_t)m * 64 + t) * 16 + k] : (bf16)0.f;
}

__global__ void cvt_bf16(const float* __restrict__ s, bf16* __restrict__ d, int n) {
  int i = blockIdx.x * blockDim.x + threadIdx.x;
  if (i < n) d[i] = (bf16)s[i];
}

// ---------------------------------------------------------------------------
extern "C" void kernel_launch(void* const* d_in, const int* in_sizes, int n_in,
                              void* d_out, int out_size, void* d_ws, size_t ws_size,
                              hipStream_t stream) {
  (void)in_sizes; (void)n_in; (void)out_size; (void)ws_size;
  const float* in_data = (const float*)d_in[0];
  const float* last_loc = (const float*)d_in[1];
  const float* eWih0 = (const float*)d_in[3];
  const float* eWhh0 = (const float*)d_in[4];
  const float* ebih0 = (const float*)d_in[5];
  const float* ebhh0 = (const float*)d_in[6];
  const float* eWih1 = (const float*)d_in[7];
  const float* eWhh1 = (const float*)d_in[8];
  const float* ebih1 = (const float*)d_in[9];
  const float* ebhh1 = (const float*)d_in[10];
  const float* dWih0 = (const float*)d_in[11];
  const float* dWhh0 = (const float*)d_in[12];
  const float* dbih0 = (const float*)d_in[13];
  const float* dbhh0 = (const float*)d_in[14];
  const float* dWih1 = (const float*)d_in[15];
  const float* dWhh1 = (const float*)d_in[16];
  const float* dbih1 = (const float*)d_in[17];
  const float* dbhh1 = (const float*)d_in[18];
  const float* linW = (const float*)d_in[19];
  const float* linb = (const float*)d_in[20];
  float* outp = (float*)d_out;

  uint8_t* base = (uint8_t*)d_ws;
  size_t off = 0;
  auto alloc = [&](size_t bytes) -> void* {
    void* p = base + off;
    off += (bytes + 255) & ~(size_t)255;
    return p;
  };
  bf16* WtE0 = (bf16*)alloc(2880ull * 992 * 2);
  bf16* WtE1 = (bf16*)alloc(2880ull * 1920 * 2);
  bf16* WtD0a = (bf16*)alloc(2880ull * 992 * 2);
  bf16* WtD0 = (bf16*)alloc(2880ull * 1920 * 2);
  bf16* WtD1 = (bf16*)alloc(2880ull * 1920 * 2);
  bf16* linWb = (bf16*)alloc(32ull * 960 * 2);
  float* bA_e0 = (float*)alloc(2880 * 4); float* bB_e0 = (float*)alloc(2880 * 4);
  float* bA_e1 = (float*)alloc(2880 * 4); float* bB_e1 = (float*)alloc(2880 * 4);
  float* bA_d0a = (float*)alloc(2880 * 4); float* bB_d0a = (float*)alloc(2880 * 4);
  float* bA_d0 = (float*)alloc(2880 * 4); float* bB_d0 = (float*)alloc(2880 * 4);
  float* bA_d1 = (float*)alloc(2880 * 4); float* bB_d1 = (float*)alloc(2880 * 4);
  bf16* Xenc = (bf16*)alloc(64ull * 512 * 32 * 2);
  bf16* Xloc = (bf16*)alloc(512ull * 32 * 2);
  const int HS_ELEMS = 512 * 960;
  float* states = (float*)alloc((size_t)HS_ELEMS * (4 * 4 + 4 * 2));
  float* h0f[2] = {states, states + HS_ELEMS};
  float* h1f[2] = {states + 2 * HS_ELEMS, states + 3 * HS_ELEMS};
  bf16* bstates = (bf16*)(states + 4 * HS_ELEMS);
  bf16* h0b[2] = {bstates, bstates + HS_ELEMS};
  bf16* h1b[2] = {bstates + 2 * HS_ELEMS, bstates + 3 * HS_ELEMS};

  // ---- prep ----
  hipMemsetAsync(states, 0, (size_t)HS_ELEMS * (4 * 4 + 4 * 2), stream);
  prep_weight<<<4096, 256, 0, stream>>>(eWih0, eWhh0, WtE0, 16, 32, 992);
  prep_weight<<<8192, 256, 0, stream>>>(eWih1, eWhh1, WtE1, 960, 960, 1920);
  prep_weight<<<4096, 256, 0, stream>>>(dWih0, dWhh0, WtD0a, 32, 32, 992);
  prep_weight_dec0<<<8192, 256, 0, stream>>>(dWih0, dWhh0, linW, WtD0);
  prep_weight<<<8192, 256, 0, stream>>>(dWih1, dWhh1, WtD1, 960, 960, 1920);
  prep_bias<<<12, 256, 0, stream>>>(ebih0, ebhh0, bA_e0, bB_e0);
  prep_bias<<<12, 256, 0, stream>>>(ebih1, ebhh1, bA_e1, bB_e1);
  prep_bias<<<12, 256, 0, stream>>>(dbih0, dbhh0, bA_d0a, bB_d0a);
  prep_bias_dec0<<<12, 256, 0, stream>>>(dbih0, dbhh0, dWih0, linb, bA_d0, bB_d0);
  prep_bias<<<12, 256, 0, stream>>>(dbih1, dbhh1, bA_d1, bB_d1);
  prep_xenc<<<(64 * 512 * 32 + 255) / 256, 256, 0, stream>>>(in_data, Xenc);
  cvt_bf16<<<(512 * 32 + 255) / 256, 256, 0, stream>>>(last_loc, Xloc, 512 * 32);
  cvt_bf16<<<(32 * 960 + 255) / 256, 256, 0, stream>>>(linW, linWb, 32 * 960);

  auto step_args = [](const bf16* X, int ldx, const bf16* Hb, const bf16* Wt,
                      const float* bA, const float* bB, int KXPAD, int Ktot,
                      const float* Hfp, float* Hfn, bf16* Hbn, float* oh) {
    StepArgs s;
    s.X = X; s.ldx = ldx; s.Hb = Hb; s.Wt = Wt; s.bA = bA; s.bB = bB;
    s.KXPAD = KXPAD; s.Ktot = Ktot; s.Hf_prev = Hfp; s.Hf_next = Hfn;
    s.Hb_next = Hbn; s.out_hidden = oh; s._pad = 0;
    return s;
  };

  int p0 = 0, p1 = 0;
  // ---- encoder (L0 step t fused with L1 step t-1) ----
  {
    StepArgs s = step_args(Xenc, 32, h0b[p0], WtE0, bA_e0, bB_e0, 32, 992,
                           h0f[p0], h0f[1 - p0], h0b[1 - p0], nullptr);
    gru_step<<<dim3(256, 1, 1), 256, 0, stream>>>(s, s);
    p0 ^= 1;
  }
  for (int t = 1; t < 64; ++t) {
    StepArgs s0 = step_args(Xenc + (size_t)t * 512 * 32, 32, h0b[p0], WtE0, bA_e0, bB_e0, 32, 992,
                            h0f[p0], h0f[1 - p0], h0b[1 - p0], nullptr);
    StepArgs s1 = step_args(h0b[p0], 960, h1b[p1], WtE1, bA_e1, bB_e1, 960, 1920,
                            h1f[p1], h1f[1 - p1], h1b[1 - p1], nullptr);
    gru_step<<<dim3(256, 1, 2), 256, 0, stream>>>(s0, s1);
    p0 ^= 1; p1 ^= 1;
  }
  {
    StepArgs s1 = step_args(h0b[p0], 960, h1b[p1], WtE1, bA_e1, bB_e1, 960, 1920,
                            h1f[p1], h1f[1 - p1], h1b[1 - p1], nullptr);
    gru_step<<<dim3(256, 1, 1), 256, 0, stream>>>(s1, s1);
    p1 ^= 1;
  }
  // ---- decoder ----
  float* hid = outp + 786432;  // hidden_outputs base (512 x 48 x 1920)
  for (int t = 0; t < 48; ++t) {
    StepArgs s0;
    if (t == 0)
      s0 = step_args(Xloc, 32, h0b[p0], WtD0a, bA_d0a, bB_d0a, 32, 992,
                     h0f[p0], h0f[1 - p0], h0b[1 - p0], hid + (size_t)t * 1920);
    else
      s0 = step_args(h1b[p1], 960, h0b[p0], WtD0, bA_d0, bB_d0, 960, 1920,
                     h0f[p0], h0f[1 - p0], h0b[1 - p0], hid + (size_t)t * 1920);
    gru_step<<<dim3(256, 1, 1), 256, 0, stream>>>(s0, s0);
    p0 ^= 1;
    StepArgs s1 = step_args(h0b[p0], 960, h1b[p1], WtD1, bA_d1, bB_d1, 960, 1920,
                            h1f[p1], h1f[1 - p1], h1b[1 - p1], hid + (size_t)t * 1920 + 960);
    gru_step<<<dim3(256, 1, 1), 256, 0, stream>>>(s1, s1);
    p1 ^= 1;
  }
  // ---- all 48 outputs in one batched GEMM from stored h1 ----
  final_linear<<<384, 256, 0, stream>>>(hid, linWb, linb, outp);
}